// Round 1
// baseline (2155.768 us; speedup 1.0000x reference)
//
#include <hip/hip_runtime.h>

typedef _Float16 f16;
typedef _Float16 f16x8 __attribute__((ext_vector_type(8)));
typedef float f32x4 __attribute__((ext_vector_type(4)));

#define B_ 4096
#define N_ 32768
#define D_ 1024
#define BM 32
#define BN 128
#define THREADS 512

__device__ __forceinline__ f32x4 mfma16(f16x8 a, f16x8 b, f32x4 c) {
    return __builtin_amdgcn_mfma_f32_16x16x32_f16(a, b, c, 0, 0, 0);
}

// ---- swizzled LDS addressing -------------------------------------------------
// X tiles: [row][d] row-major, row stride 2048B, XOR bits 4-6 with row&7.
__device__ __forceinline__ const f16x8* xfrag(const f16* base, int row, int d0) {
    int off = (row << 11) + (d0 << 1);
    off ^= (row & 7) << 4;
    return reinterpret_cast<const f16x8*>(reinterpret_cast<const char*>(base) + off);
}
__device__ __forceinline__ f16x8* xfrag_w(f16* base, int row, int d0) {
    int off = (row << 11) + (d0 << 1);
    off ^= (row & 7) << 4;
    return reinterpret_cast<f16x8*>(reinterpret_cast<char*>(base) + off);
}
// P tile: [m][kv] row-major, row stride 256B, same XOR scheme.
__device__ __forceinline__ const f16x8* pfrag(const f16* base, int m, int kv0) {
    int off = (m << 8) + (kv0 << 1);
    off ^= (m & 7) << 4;
    return reinterpret_cast<const f16x8*>(reinterpret_cast<const char*>(base) + off);
}
__device__ __forceinline__ f16* pelem(f16* base, int m, int kv) {
    int off = (m << 8) + (kv << 1);
    off ^= (m & 7) << 4;
    return reinterpret_cast<f16*>(reinterpret_cast<char*>(base) + off);
}

// ---- convert K (fp32 -> f16, same layout) -----------------------------------
__global__ void conv_k16(const float* __restrict__ src, f16* __restrict__ dst) {
    size_t i = ((size_t)blockIdx.x * blockDim.x + threadIdx.x) * 8;
    const float4* s = (const float4*)(src + i);
    float4 a = s[0], b = s[1];
    f16x8 h;
    h[0] = (f16)a.x; h[1] = (f16)a.y; h[2] = (f16)a.z; h[3] = (f16)a.w;
    h[4] = (f16)b.x; h[5] = (f16)b.y; h[6] = (f16)b.z; h[7] = (f16)b.w;
    *(f16x8*)(dst + i) = h;
}

// ---- convert + transpose V: V[N][D] fp32 -> VT[D][N] f16 ---------------------
__global__ void conv_vt(const float* __restrict__ V, f16* __restrict__ VT) {
    __shared__ f16 tile[64][65];
    int n0 = blockIdx.x << 6, d0 = blockIdx.y << 6;
    for (int idx = threadIdx.x; idx < 4096; idx += 256) {
        int i = idx >> 6, j = idx & 63;           // i: n offset, j: d offset
        tile[j][i] = (f16)V[(size_t)(n0 + i) * D_ + d0 + j];
    }
    __syncthreads();
    for (int idx = threadIdx.x; idx < 4096; idx += 256) {
        int j = idx >> 6, i = idx & 63;
        VT[(size_t)(d0 + j) * N_ + n0 + i] = tile[j][i];
    }
}

// ---- main fused attention kernel --------------------------------------------
// USE_WS=1: f16 K_h / VT from workspace, NSPLIT=2 (writes partials).
// USE_WS=0: fp32 direct loads (slow fallback), NSPLIT=1 (writes Out).
template<int USE_WS>
__global__ __launch_bounds__(THREADS, 2)
void attn_main(const float* __restrict__ Xg, const float* __restrict__ Kg,
               const float* __restrict__ Vg, const f16* __restrict__ Kh,
               const f16* __restrict__ VT, float* __restrict__ Opart,
               float* __restrict__ Mpart, float* __restrict__ Lpart,
               float* __restrict__ Outg)
{
    __shared__ __align__(16) f16 Xhi[BM * D_];   // 64 KB
    __shared__ __align__(16) f16 Xlo[BM * D_];   // 64 KB
    __shared__ __align__(16) f16 Pl[BM * BN];    // 8 KB
    __shared__ float redm[8][BM];
    __shared__ float reds[8][BM];

    int bblk, chunk, kvbase, iters;
    if (USE_WS) {
        int xcd = blockIdx.x & 7;
        chunk  = xcd >> 2;                               // XCDs 0-3 -> chunk0, 4-7 -> chunk1
        bblk   = ((blockIdx.x >> 3) << 2) | (xcd & 3);   // 0..127, bijective
        kvbase = chunk * (N_ / 2);
        iters  = (N_ / 2) / BN;                          // 128
    } else {
        chunk = 0; bblk = blockIdx.x; kvbase = 0; iters = N_ / BN; // 256
    }
    const int b0 = bblk * BM;
    const int t  = threadIdx.x;

    // --- stage X: fp32 -> f16 hi/lo into swizzled LDS ---
    for (int c = t; c < BM * D_ / 8; c += THREADS) {
        int row = c >> 7;
        int d0  = (c & 127) << 3;
        const float4* s = (const float4*)(Xg + (size_t)(b0 + row) * D_ + d0);
        float4 a = s[0], b = s[1];
        f16x8 hi, lo;
        hi[0] = (f16)a.x; lo[0] = (f16)(a.x - (float)hi[0]);
        hi[1] = (f16)a.y; lo[1] = (f16)(a.y - (float)hi[1]);
        hi[2] = (f16)a.z; lo[2] = (f16)(a.z - (float)hi[2]);
        hi[3] = (f16)a.w; lo[3] = (f16)(a.w - (float)hi[3]);
        hi[4] = (f16)b.x; lo[4] = (f16)(b.x - (float)hi[4]);
        hi[5] = (f16)b.y; lo[5] = (f16)(b.y - (float)hi[5]);
        hi[6] = (f16)b.z; lo[6] = (f16)(b.z - (float)hi[6]);
        hi[7] = (f16)b.w; lo[7] = (f16)(b.w - (float)hi[7]);
        *xfrag_w(Xhi, row, d0) = hi;
        *xfrag_w(Xlo, row, d0) = lo;
    }
    __syncthreads();

    const int wave = t >> 6, lane = t & 63;
    const int l15 = lane & 15, lg = lane >> 4, lg8 = lg << 3;

    f32x4 O[2][8];
    #pragma unroll
    for (int fm = 0; fm < 2; ++fm)
        #pragma unroll
        for (int fn = 0; fn < 8; ++fn) O[fm][fn] = (f32x4){0.f, 0.f, 0.f, 0.f};
    float mrun[8], lrun[8];
    #pragma unroll
    for (int i = 0; i < 8; ++i) { mrun[i] = -INFINITY; lrun[i] = 0.f; }

    const f16*   kb = USE_WS ? (Kh + (size_t)(kvbase + wave * 16 + l15) * D_ + lg8) : nullptr;
    const float* kf = Kg + (size_t)(kvbase + wave * 16 + l15) * D_ + lg8;
    const f16*   vb = USE_WS ? (VT + (size_t)(wave * 128 + l15) * N_ + kvbase + lg8) : nullptr;

    for (int it = 0; it < iters; ++it) {
        const int kv0 = it * BN;   // relative to chunk base

        // ---- QK^T: wave computes S[32][16] for its 16-row KV strip ----
        f32x4 S0 = {0.f, 0.f, 0.f, 0.f}, S1 = {0.f, 0.f, 0.f, 0.f};
        #pragma unroll 4
        for (int ks = 0; ks < D_ / 32; ++ks) {
            f16x8 bk;
            if (USE_WS) {
                bk = *(const f16x8*)(kb + (size_t)kv0 * D_ + ks * 32);
            } else {
                const float* kp = kf + (size_t)kv0 * D_ + ks * 32;
                float4 q0 = *(const float4*)kp, q1 = *(const float4*)(kp + 4);
                bk[0] = (f16)q0.x; bk[1] = (f16)q0.y; bk[2] = (f16)q0.z; bk[3] = (f16)q0.w;
                bk[4] = (f16)q1.x; bk[5] = (f16)q1.y; bk[6] = (f16)q1.z; bk[7] = (f16)q1.w;
            }
            int d0 = ks * 32 + lg8;
            f16x8 ah0 = *xfrag(Xhi, l15,      d0);
            f16x8 ah1 = *xfrag(Xhi, l15 + 16, d0);
            S0 = mfma16(ah0, bk, S0);
            S1 = mfma16(ah1, bk, S1);
            f16x8 al0 = *xfrag(Xlo, l15,      d0);
            f16x8 al1 = *xfrag(Xlo, l15 + 16, d0);
            S0 = mfma16(al0, bk, S0);
            S1 = mfma16(al1, bk, S1);
        }

        // ---- online softmax: strip max -> cross-wave max ----
        float sm[8];
        #pragma unroll
        for (int i = 0; i < 8; ++i) {
            float x = (i < 4) ? S0[i] : S1[i - 4];
            x = fmaxf(x, __shfl_xor(x, 1));
            x = fmaxf(x, __shfl_xor(x, 2));
            x = fmaxf(x, __shfl_xor(x, 4));
            x = fmaxf(x, __shfl_xor(x, 8));
            sm[i] = x;
        }
        if (l15 == 0) {
            #pragma unroll
            for (int i = 0; i < 8; ++i)
                redm[wave][(i >> 2) * 16 + lg * 4 + (i & 3)] = sm[i];
        }
        __syncthreads();

        float Mn[8], sc[8];
        #pragma unroll
        for (int i = 0; i < 8; ++i) {
            int m = (i >> 2) * 16 + lg * 4 + (i & 3);
            float mx = redm[0][m];
            #pragma unroll
            for (int w2 = 1; w2 < 8; ++w2) mx = fmaxf(mx, redm[w2][m]);
            Mn[i]  = fmaxf(mrun[i], mx);
            sc[i]  = __expf(mrun[i] - Mn[i]);
            mrun[i] = Mn[i];
        }

        // ---- P = exp(S - Mn); strip sums; write P to LDS (f16) ----
        float ps[8];
        #pragma unroll
        for (int i = 0; i < 8; ++i) {
            float p = __expf(((i < 4) ? S0[i] : S1[i - 4]) - Mn[i]);
            int m = (i >> 2) * 16 + lg * 4 + (i & 3);
            *pelem(Pl, m, wave * 16 + l15) = (f16)p;
            float x = p;
            x += __shfl_xor(x, 1);
            x += __shfl_xor(x, 2);
            x += __shfl_xor(x, 4);
            x += __shfl_xor(x, 8);
            ps[i] = x;
        }
        if (l15 == 0) {
            #pragma unroll
            for (int i = 0; i < 8; ++i)
                reds[wave][(i >> 2) * 16 + lg * 4 + (i & 3)] = ps[i];
        }
        __syncthreads();

        #pragma unroll
        for (int i = 0; i < 8; ++i) {
            int m = (i >> 2) * 16 + lg * 4 + (i & 3);
            float sum = reds[0][m];
            #pragma unroll
            for (int w2 = 1; w2 < 8; ++w2) sum += reds[w2][m];
            lrun[i] = lrun[i] * sc[i] + sum;
        }

        // ---- rescale O by exp(m_old - m_new) ----
        #pragma unroll
        for (int fm = 0; fm < 2; ++fm)
            #pragma unroll
            for (int fn = 0; fn < 8; ++fn)
                #pragma unroll
                for (int r = 0; r < 4; ++r)
                    O[fm][fn][r] *= sc[fm * 4 + r];

        // ---- PV: O[32][128-slice] += P[32][128] * V[128][slice] ----
        #pragma unroll
        for (int ks = 0; ks < 4; ++ks) {
            f16x8 pa0 = *pfrag(Pl, l15,      ks * 32 + lg8);
            f16x8 pa1 = *pfrag(Pl, l15 + 16, ks * 32 + lg8);
            #pragma unroll
            for (int fn = 0; fn < 8; ++fn) {
                f16x8 bv;
                if (USE_WS) {
                    bv = *(const f16x8*)(vb + (size_t)(fn * 16) * N_ + kv0 + ks * 32);
                } else {
                    #pragma unroll
                    for (int j = 0; j < 8; ++j)
                        bv[j] = (f16)Vg[(size_t)(kvbase + kv0 + ks * 32 + lg8 + j) * D_
                                        + wave * 128 + fn * 16 + l15];
                }
                O[0][fn] = mfma16(pa0, bv, O[0][fn]);
                O[1][fn] = mfma16(pa1, bv, O[1][fn]);
            }
        }
    }

    // ---- epilogue ----
    if (USE_WS) {
        float* Op = Opart + (size_t)chunk * B_ * D_;
        #pragma unroll
        for (int fm = 0; fm < 2; ++fm)
            #pragma unroll
            for (int fn = 0; fn < 8; ++fn)
                #pragma unroll
                for (int r = 0; r < 4; ++r) {
                    int row = b0 + fm * 16 + lg * 4 + r;
                    int col = wave * 128 + fn * 16 + l15;
                    Op[(size_t)row * D_ + col] = O[fm][fn][r];
                }
        if (wave == 0 && l15 == 0) {
            #pragma unroll
            for (int i = 0; i < 8; ++i) {
                int row = b0 + (i >> 2) * 16 + lg * 4 + (i & 3);
                Mpart[(size_t)chunk * B_ + row] = mrun[i];
                Lpart[(size_t)chunk * B_ + row] = lrun[i];
            }
        }
    } else {
        #pragma unroll
        for (int fm = 0; fm < 2; ++fm)
            #pragma unroll
            for (int r = 0; r < 4; ++r) {
                float inv = 1.f / lrun[fm * 4 + r];
                #pragma unroll
                for (int fn = 0; fn < 8; ++fn) {
                    int row = b0 + fm * 16 + lg * 4 + r;
                    int col = wave * 128 + fn * 16 + l15;
                    Outg[(size_t)row * D_ + col] = O[fm][fn][r] * inv;
                }
            }
    }
}

// ---- combine NSPLIT=2 partials ----------------------------------------------
__global__ void combine_k(const float* __restrict__ Opart,
                          const float* __restrict__ Mp, const float* __restrict__ Lp,
                          float* __restrict__ Outg)
{
    int b = blockIdx.x;
    float m0 = Mp[b], m1 = Mp[B_ + b];
    float l0 = Lp[b], l1 = Lp[B_ + b];
    float M  = fmaxf(m0, m1);
    float w0 = __expf(m0 - M), w1 = __expf(m1 - M);
    float inv = 1.f / (w0 * l0 + w1 * l1);
    const float4* O0 = (const float4*)(Opart + (size_t)b * D_);
    const float4* O1 = (const float4*)(Opart + (size_t)B_ * D_ + (size_t)b * D_);
    float4* o = (float4*)(Outg + (size_t)b * D_);
    for (int i = threadIdx.x; i < D_ / 4; i += blockDim.x) {
        float4 a = O0[i], c = O1[i];
        float4 r;
        r.x = (w0 * a.x + w1 * c.x) * inv;
        r.y = (w0 * a.y + w1 * c.y) * inv;
        r.z = (w0 * a.z + w1 * c.z) * inv;
        r.w = (w0 * a.w + w1 * c.w) * inv;
        o[i] = r;
    }
}

extern "C" void kernel_launch(void* const* d_in, const int* in_sizes, int n_in,
                              void* d_out, int out_size, void* d_ws, size_t ws_size,
                              hipStream_t stream) {
    const float* X = (const float*)d_in[0];
    const float* K = (const float*)d_in[1];
    const float* V = (const float*)d_in[2];
    float* Out = (float*)d_out;

    const size_t szKh = (size_t)N_ * D_ * sizeof(f16);      // 64 MiB
    const size_t szVT = (size_t)N_ * D_ * sizeof(f16);      // 64 MiB
    const size_t szOp = 2ull * B_ * D_ * sizeof(float);     // 32 MiB
    const size_t szM  = 2ull * B_ * sizeof(float);
    const size_t need = szKh + szVT + szOp + 2 * szM;

    if (ws_size >= need && d_ws != nullptr) {
        f16*   Kh = (f16*)d_ws;
        f16*   VT = (f16*)((char*)d_ws + szKh);
        float* Op = (float*)((char*)d_ws + szKh + szVT);
        float* Mp = (float*)((char*)Op + szOp);
        float* Lp = (float*)((char*)Mp + szM);

        conv_k16<<<(N_ * D_ / 8) / 256, 256, 0, stream>>>(K, Kh);
        conv_vt<<<dim3(N_ / 64, D_ / 64), 256, 0, stream>>>(V, VT);
        attn_main<1><<<256, THREADS, 0, stream>>>(X, K, V, Kh, VT, Op, Mp, Lp, Out);
        combine_k<<<B_, 256, 0, stream>>>(Op, Mp, Lp, Out);
    } else {
        // Slow but correct fallback: fp32 operands read directly, no N-split.
        attn_main<0><<<B_ / BM, THREADS, 0, stream>>>(X, K, V, nullptr, nullptr,
                                                      nullptr, nullptr, nullptr, Out);
    }
}